// Round 10
// baseline (188.437 us; speedup 1.0000x reference)
//
#include <hip/hip_runtime.h>
#include <hip/hip_bf16.h>

typedef unsigned int u32;
typedef __attribute__((ext_vector_type(4))) float f32x4;

#define NPAIR 32
#define NCLS  92
#define NCTX  8
#define MAXL  40
#define DIM   768
#define LSUF  31

#define MAT_ELEMS 90439680u      // 32*92*40*768  (f32 elements)
#define MASK_BASE 180879360u     // 2*MAT_ELEMS (f32 element offset)
#define NBLK_D1   1472u          // 2*92*8 token-quads
#define MASK_F4   29440u         // 117760/4
#define NBLK_MASK 115u           // 29440/256

// d_ws layout (f32 offsets): att[0 .. 49152), h[49152 .. 57344), so_e[57344 .. 106496)
#define WS_ATT  0u
#define WS_H    49152u
#define WS_SOE  57344u

// ---------------- kernel A: h = relu(so @ W1 + b1) ----------------
__global__ __launch_bounds__(512) void k_h(
    const int* __restrict__ so_ids,
    const float* __restrict__ enti,     // (36,256)
    const float* __restrict__ W1,       // (512,256)
    const float* __restrict__ b1,       // (256)
    float* __restrict__ ws)
{
    const int p = blockIdx.x;
    const int t = threadIdx.x;
    __shared__ float so_vec[512];
    __shared__ float w1part[2][256];
    __shared__ int ids[2];

    if (t == 0) {
        bool is64 = true;
        for (int i = 1; i < 64; i += 2) is64 = is64 && (so_ids[i] == 0);
        if (is64) { ids[0] = so_ids[4 * p];     ids[1] = so_ids[4 * p + 2]; }
        else      { ids[0] = so_ids[2 * p];     ids[1] = so_ids[2 * p + 1]; }
    }
    __syncthreads();
    so_vec[t] = (t < 256) ? enti[ids[0] * 256 + t] : enti[ids[1] * 256 + (t - 256)];
    __syncthreads();

    const int j = t & 255, half = t >> 8;
    const float* w = W1 + (half * 256) * 256 + j;
    const float* sv = so_vec + half * 256;
    float acc = 0.f;
    #pragma unroll 8
    for (int kk = 0; kk < 256; ++kk)
        acc = fmaf(sv[kk], w[(size_t)kk * 256], acc);
    w1part[half][j] = acc;
    __syncthreads();
    if (t < 256)
        ws[WS_H + p * 256 + t] = fmaxf(w1part[0][t] + w1part[1][t] + b1[t], 0.f);
}

// ---------------- kernel B: so_e = h @ W2 ----------------
__global__ __launch_bounds__(256) void k_soe(
    const float* __restrict__ W2,       // (256,1536)
    float* __restrict__ ws)
{
    const int p = blockIdx.x / 6;
    const int cc = blockIdx.x % 6;
    const int t = threadIdx.x;
    __shared__ float hl[256];
    hl[t] = ws[WS_H + p * 256 + t];
    __syncthreads();

    const int c = cc * 256 + t;
    const float* w = W2 + c;
    float acc = 0.f;
    #pragma unroll 8
    for (int k = 0; k < 256; ++k)
        acc = fmaf(hl[k], w[(size_t)k * 1536], acc);
    ws[WS_SOE + p * 1536 + c] = acc;
}

// ---------------- kernel C: softmax attention ----------------
__global__ __launch_bounds__(256) void k_att(
    const float* __restrict__ meta,     // (8,768)
    float* __restrict__ ws)
{
    const int which = blockIdx.x >> 5;
    const int p = blockIdx.x & 31;
    const int t = threadIdx.x;
    __shared__ float red[8][256];
    __shared__ float probs[8];

    const float* q = ws + WS_SOE + p * 1536 + which * DIM;
    float qr[3];
    #pragma unroll
    for (int i = 0; i < 3; ++i) qr[i] = q[t + 256 * i];

    #pragma unroll
    for (int c = 0; c < 8; ++c) {
        float pp = 0.f;
        #pragma unroll
        for (int i = 0; i < 3; ++i)
            pp = fmaf(qr[i], meta[c * DIM + t + 256 * i], pp);
        red[c][t] = pp;
    }
    __syncthreads();
    for (int s = 128; s > 0; s >>= 1) {
        if (t < s) {
            #pragma unroll
            for (int c = 0; c < 8; ++c)
                red[c][t] += red[c][t + s];
        }
        __syncthreads();
    }
    if (t == 0) {
        const float scale = 0.036084391824351615f;  // 1/sqrt(768)
        float sc[8], m = -1e30f;
        #pragma unroll
        for (int c = 0; c < 8; ++c) { sc[c] = red[c][0] * scale; m = fmaxf(m, sc[c]); }
        float sum = 0.f;
        #pragma unroll
        for (int c = 0; c < 8; ++c) { sc[c] = expf(sc[c] - m); sum += sc[c]; }
        const float inv = 1.f / sum;
        #pragma unroll
        for (int c = 0; c < 8; ++c) probs[c] = sc[c] * inv;
    }
    __syncthreads();
    #pragma unroll
    for (int i = 0; i < 3; ++i) {
        const int d = t + 256 * i;
        float a = 0.f;
        #pragma unroll
        for (int c = 0; c < 8; ++c)
            a = fmaf(probs[c], meta[c * DIM + d], a);
        ws[WS_ATT + (which * NPAIR + p) * DIM + d] = a;
    }
}

// ---------------- kernel D1: prefix/suffix replicator (LDS-staged, PLAIN stores) ----------------
// block = (which, cls, tq of 4 tokens from {0, 9..39}); stage 12 KB once,
// write to all 32 pairs. Mask tail appended to the grid.
__global__ __launch_bounds__(256) void k_copy(
    const float* __restrict__ prefix,   // (133,1,768)
    const float* __restrict__ suffix,   // (133,31,768)
    const int* __restrict__ tok_mask,   // (133,40) int32
    float* __restrict__ out)
{
    const u32 bid = blockIdx.x;
    const u32 t = threadIdx.x;

    if (bid < NBLK_D1) {
        const u32 which = bid / (NCLS * 8u);
        const u32 rem = bid - which * (NCLS * 8u);
        const u32 cls = rem / 8u;
        const u32 tq = rem - cls * 8u;

        __shared__ __align__(16) float srcl[4 * DIM];
        for (u32 u = t; u < 4u * 192u; u += 256u) {   // 768 f32x4 units
            const u32 j = u / 192u;
            const u32 dpos = u - j * 192u;
            const u32 rtok = (tq == 0u) ? (j == 0u ? 0u : 8u + j) : (8u + 4u * tq + j);
            const float* src = (rtok == 0u)
                ? (prefix + (size_t)(cls + 1u) * DIM + dpos * 4u)
                : (suffix + ((size_t)(cls + 1u) * LSUF + (rtok - 9u)) * DIM + dpos * 4u);
            *(f32x4*)(srcl + u * 4u) = *(const f32x4*)src;
        }
        __syncthreads();

        for (u32 pair = 0; pair < NPAIR; ++pair) {
            float* slab = out + (size_t)which * MAT_ELEMS
                              + ((size_t)(pair * NCLS + cls) * MAXL) * DIM;
            #pragma unroll
            for (u32 uu = 0; uu < 3u; ++uu) {
                const u32 u = uu * 256u + t;
                const u32 j = u / 192u;                     // wave-uniform
                const u32 dpos = u - j * 192u;
                const u32 rtok = (tq == 0u) ? (j == 0u ? 0u : 8u + j) : (8u + 4u * tq + j);
                *(f32x4*)(slab + (size_t)rtok * DIM + dpos * 4u) =
                    *(const f32x4*)(srcl + u * 4u);
            }
        }
    } else {
        const u32 idx4 = (bid - NBLK_D1) * 256u + t;
        if (idx4 < MASK_F4) {
            const u32 m = idx4 * 4u;
            f32x4 v;
            #pragma unroll
            for (int j = 0; j < 4; ++j) {
                const u32 i = m + (u32)j;
                const u32 rw = i / 40u;
                const u32 tk = i - rw * 40u;
                const u32 cls = rw % 92u;
                v[j] = (float)tok_mask[(cls + 1u) * 40u + tk];
            }
            *(f32x4*)(out + MASK_BASE + m) = v;
        }
    }
}

// ---------------- kernel D2: ctx+att materializer (LDS-staged sums, PLAIN stores) ----------------
// block = (which, pair, cls-group of 23); compute 8 summed rows once (24 KB),
// write them to 23 cls slabs (tokens 1..8 contiguous).
__global__ __launch_bounds__(256) void k_ctx(
    const float* __restrict__ sctx,     // (8,768)
    const float* __restrict__ octx,     // (8,768)
    const float* __restrict__ att,      // (2,32,768) (in d_ws)
    float* __restrict__ out)
{
    const u32 bid = blockIdx.x;         // 256 = 2*32*4
    const u32 t = threadIdx.x;
    const u32 which = bid / 128u;
    const u32 rem = bid - which * 128u;
    const u32 pair = rem / 4u;
    const u32 cg = rem & 3u;

    const float* ctx = which ? octx : sctx;
    const float* ar = att + (size_t)(which * NPAIR + pair) * DIM;

    __shared__ __align__(16) float sums[8 * DIM];
    for (u32 u = t; u < 8u * 192u; u += 256u) {       // 1536 f32x4 units
        const u32 dpos = u % 192u;
        const f32x4 v = *(const f32x4*)(ctx + (size_t)u * 4u)
                      + *(const f32x4*)(ar + (size_t)dpos * 4u);
        *(f32x4*)(sums + u * 4u) = v;
    }
    __syncthreads();

    for (u32 c = 0; c < 23u; ++c) {
        const u32 cls = cg * 23u + c;
        float* base = out + (size_t)which * MAT_ELEMS
                          + ((size_t)(pair * NCLS + cls) * MAXL + 1u) * DIM;
        #pragma unroll
        for (u32 uu = 0; uu < 6u; ++uu) {
            const u32 u = uu * 256u + t;
            *(f32x4*)(base + (size_t)u * 4u) = *(const f32x4*)(sums + u * 4u);
        }
    }
}

extern "C" void kernel_launch(void* const* d_in, const int* in_sizes, int n_in,
                              void* d_out, int out_size, void* d_ws, size_t ws_size,
                              hipStream_t stream) {
    const int* so_ids     = (const int*)d_in[0];
    const float* enti     = (const float*)d_in[1];
    const float* prefix   = (const float*)d_in[2];
    const float* suffix   = (const float*)d_in[3];
    const int* tok_mask   = (const int*)d_in[4];
    const float* meta     = (const float*)d_in[5];
    const float* sctx     = (const float*)d_in[6];
    const float* octx     = (const float*)d_in[7];
    const float* W1       = (const float*)d_in[8];
    const float* b1       = (const float*)d_in[9];
    const float* W2       = (const float*)d_in[10];
    float* ws = (float*)d_ws;   // 426 KB used: att | h | so_e

    k_h  <<<dim3(NPAIR), dim3(512), 0, stream>>>(so_ids, enti, W1, b1, ws);
    k_soe<<<dim3(192),   dim3(256), 0, stream>>>(W2, ws);
    k_att<<<dim3(64),    dim3(256), 0, stream>>>(meta, ws);
    k_ctx<<<dim3(256),   dim3(256), 0, stream>>>(sctx, octx, ws + WS_ATT, (float*)d_out);
    k_copy<<<dim3(NBLK_D1 + NBLK_MASK), dim3(256), 0, stream>>>(
        prefix, suffix, tok_mask, (float*)d_out);
}

// Round 11
// 156.350 us; speedup vs baseline: 1.2052x; 1.2052x over previous
//
#include <hip/hip_runtime.h>
#include <hip/hip_bf16.h>

typedef unsigned int u32;
typedef __attribute__((ext_vector_type(4))) float f32x4;

#define NPAIR 32
#define NCLS  92
#define NCTX  8
#define MAXL  40
#define DIM   768
#define LSUF  31

#define MAT_ELEMS 90439680u      // 32*92*40*768  (f32 elements)
#define MASK_BASE 180879360u     // 2*MAT_ELEMS (f32 element offset)

#define NBLK_CTX  64u            // (which, pair)
#define NBLK_D1   1472u          // (which, cls, token-quad)
#define NBLK_MASK 115u           // 115*256*4 = 117760 mask elems
#define NBLK_ALL  (NBLK_CTX + NBLK_D1 + NBLK_MASK)   // 1651

// ONE kernel: ctx blocks (MLP computed redundantly in-block) + copy blocks + mask.
// 24 KB LDS arena shared by all roles; NT stores throughout (R10 A/B: NT is +17us).
__global__ __launch_bounds__(256) void k_fused(
    const int* __restrict__ so_ids,     // (32,2) int32
    const float* __restrict__ enti,     // (36,256)
    const float* __restrict__ prefix,   // (133,1,768)
    const float* __restrict__ suffix,   // (133,31,768)
    const int* __restrict__ tok_mask,   // (133,40) int32
    const float* __restrict__ meta,     // (8,768)
    const float* __restrict__ sctx,     // (8,768)
    const float* __restrict__ octx,     // (8,768)
    const float* __restrict__ W1,       // (512,256)
    const float* __restrict__ b1,       // (256)
    const float* __restrict__ W2,       // (256,1536)
    float* __restrict__ out)
{
    const u32 bid = blockIdx.x;
    const u32 t = threadIdx.x;
    __shared__ __align__(16) float arena[8 * DIM];   // 24 KB
    __shared__ int ids[2];

    if (bid < NBLK_CTX) {
        // ---------------- ctx role: MLP + softmax-attention + 8-row broadcast ----------------
        const u32 which = bid >> 5;
        const u32 pair = bid & 31u;

        if (t == 0) {
            bool is64 = true;
            for (int i = 1; i < 64; i += 2) is64 = is64 && (so_ids[i] == 0);
            if (is64) { ids[0] = so_ids[4 * pair]; ids[1] = so_ids[4 * pair + 2]; }
            else      { ids[0] = so_ids[2 * pair]; ids[1] = so_ids[2 * pair + 1]; }
        }
        __syncthreads();

        float* so_vec = arena;            // [0, 512)
        float* h      = arena + 512;      // [512, 768)
        float* soe    = arena + 768;      // [768, 2304)
        float* red    = arena + 2304;     // [2304, 4352)  8x256
        float* probs  = arena + 4352;     // [4352, 4360)

        so_vec[t]        = enti[ids[0] * 256 + t];
        so_vec[256 + t]  = enti[ids[1] * 256 + t];
        __syncthreads();

        // h = relu(so @ W1 + b1): thread t owns column t
        {
            float acc = b1[t];
            const float* w = W1 + t;
            #pragma unroll 8
            for (int k = 0; k < 512; ++k)
                acc = fmaf(so_vec[k], w[(size_t)k * 256], acc);
            h[t] = fmaxf(acc, 0.f);
        }
        __syncthreads();

        // so_e = h @ W2: 6 columns per thread
        {
            float a6[6] = {0.f, 0.f, 0.f, 0.f, 0.f, 0.f};
            const float* w = W2 + t;
            #pragma unroll 4
            for (int k = 0; k < 256; ++k) {
                const float hk = h[k];
                #pragma unroll
                for (int r = 0; r < 6; ++r)
                    a6[r] = fmaf(hk, w[(size_t)k * 1536 + r * 256], a6[r]);
            }
            #pragma unroll
            for (int r = 0; r < 6; ++r) soe[r * 256 + t] = a6[r];
        }
        __syncthreads();

        // scores vs 8 meta rows
        const float* q = soe + which * DIM;
        float qr[3];
        #pragma unroll
        for (int i = 0; i < 3; ++i) qr[i] = q[t + 256 * i];
        #pragma unroll
        for (int c = 0; c < 8; ++c) {
            float pp = 0.f;
            #pragma unroll
            for (int i = 0; i < 3; ++i)
                pp = fmaf(qr[i], meta[c * DIM + t + 256 * i], pp);
            red[c * 256 + t] = pp;
        }
        __syncthreads();
        for (int s = 128; s > 0; s >>= 1) {
            if (t < (u32)s) {
                #pragma unroll
                for (int c = 0; c < 8; ++c)
                    red[c * 256 + t] += red[c * 256 + t + s];
            }
            __syncthreads();
        }
        if (t == 0) {
            const float scale = 0.036084391824351615f;  // 1/sqrt(768)
            float sc[8], m = -1e30f;
            #pragma unroll
            for (int c = 0; c < 8; ++c) { sc[c] = red[c * 256] * scale; m = fmaxf(m, sc[c]); }
            float sum = 0.f;
            #pragma unroll
            for (int c = 0; c < 8; ++c) { sc[c] = expf(sc[c] - m); sum += sc[c]; }
            const float inv = 1.f / sum;
            #pragma unroll
            for (int c = 0; c < 8; ++c) probs[c] = sc[c] * inv;
        }
        __syncthreads();

        // att (kept in registers), then overwrite arena with the 8 summed rows
        float pr[8];
        #pragma unroll
        for (int c = 0; c < 8; ++c) pr[c] = probs[c];
        float att_d[3];
        #pragma unroll
        for (int i = 0; i < 3; ++i) {
            const int d = t + 256 * i;
            float a = 0.f;
            #pragma unroll
            for (int c = 0; c < 8; ++c)
                a = fmaf(pr[c], meta[c * DIM + d], a);
            att_d[i] = a;
        }
        __syncthreads();   // arena fully dead

        const float* ctxg = which ? octx : sctx;
        #pragma unroll
        for (int j = 0; j < 8; ++j) {
            #pragma unroll
            for (int i = 0; i < 3; ++i) {
                const int d = t + 256 * i;
                arena[j * DIM + d] = ctxg[j * DIM + d] + att_d[i];
            }
        }
        __syncthreads();

        // stream the 24 KB block to all 92 cls slabs (tokens 1..8 contiguous)
        float* base = out + (size_t)which * MAT_ELEMS
                          + ((size_t)(pair * NCLS) * MAXL + 1u) * DIM;
        for (u32 cls = 0; cls < NCLS; ++cls) {
            float* bc = base + (size_t)cls * (MAXL * DIM);
            #pragma unroll
            for (u32 uu = 0; uu < 6u; ++uu) {
                const u32 u = uu * 256u + t;
                __builtin_nontemporal_store(*(const f32x4*)(arena + u * 4u),
                                            (f32x4*)(bc + u * 4u));
            }
        }
    } else if (bid < NBLK_CTX + NBLK_D1) {
        // ---------------- copy role: prefix/suffix replicator (LDS-staged) ----------------
        const u32 r = bid - NBLK_CTX;
        const u32 which = r / (NCLS * 8u);
        const u32 rem = r - which * (NCLS * 8u);
        const u32 cls = rem / 8u;
        const u32 tq = rem - cls * 8u;

        for (u32 u = t; u < 4u * 192u; u += 256u) {   // 768 f32x4 units (12 KB)
            const u32 j = u / 192u;
            const u32 dpos = u - j * 192u;
            const u32 rtok = (tq == 0u) ? (j == 0u ? 0u : 8u + j) : (8u + 4u * tq + j);
            const float* src = (rtok == 0u)
                ? (prefix + (size_t)(cls + 1u) * DIM + dpos * 4u)
                : (suffix + ((size_t)(cls + 1u) * LSUF + (rtok - 9u)) * DIM + dpos * 4u);
            *(f32x4*)(arena + u * 4u) = *(const f32x4*)src;
        }
        __syncthreads();

        for (u32 pair = 0; pair < NPAIR; ++pair) {
            float* slab = out + (size_t)which * MAT_ELEMS
                              + ((size_t)(pair * NCLS + cls) * MAXL) * DIM;
            #pragma unroll
            for (u32 uu = 0; uu < 3u; ++uu) {
                const u32 u = uu * 256u + t;
                const u32 j = u / 192u;                     // wave-uniform
                const u32 dpos = u - j * 192u;
                const u32 rtok = (tq == 0u) ? (j == 0u ? 0u : 8u + j) : (8u + 4u * tq + j);
                __builtin_nontemporal_store(*(const f32x4*)(arena + u * 4u),
                    (f32x4*)(slab + (size_t)rtok * DIM + dpos * 4u));
            }
        }
    } else {
        // ---------------- mask role ----------------
        const u32 idx4 = (bid - NBLK_CTX - NBLK_D1) * 256u + t;
        const u32 m = idx4 * 4u;
        f32x4 v;
        #pragma unroll
        for (int j = 0; j < 4; ++j) {
            const u32 i = m + (u32)j;
            const u32 rw = i / 40u;
            const u32 tk = i - rw * 40u;
            const u32 cls = rw % 92u;
            v[j] = (float)tok_mask[(cls + 1u) * 40u + tk];
        }
        __builtin_nontemporal_store(v, (f32x4*)(out + MASK_BASE + m));
    }
}

extern "C" void kernel_launch(void* const* d_in, const int* in_sizes, int n_in,
                              void* d_out, int out_size, void* d_ws, size_t ws_size,
                              hipStream_t stream) {
    const int* so_ids     = (const int*)d_in[0];
    const float* enti     = (const float*)d_in[1];
    const float* prefix   = (const float*)d_in[2];
    const float* suffix   = (const float*)d_in[3];
    const int* tok_mask   = (const int*)d_in[4];
    const float* meta     = (const float*)d_in[5];
    const float* sctx     = (const float*)d_in[6];
    const float* octx     = (const float*)d_in[7];
    const float* W1       = (const float*)d_in[8];
    const float* b1       = (const float*)d_in[9];
    const float* W2       = (const float*)d_in[10];

    k_fused<<<dim3(NBLK_ALL), dim3(256), 0, stream>>>(
        so_ids, enti, prefix, suffix, tok_mask, meta, sctx, octx, W1, b1, W2,
        (float*)d_out);
}

// Round 12
// 143.610 us; speedup vs baseline: 1.3121x; 1.0887x over previous
//
#include <hip/hip_runtime.h>
#include <hip/hip_bf16.h>

typedef unsigned int u32;
typedef __attribute__((ext_vector_type(4))) float f32x4;

#define NPAIR 32
#define NCLS  92
#define NCTX  8
#define MAXL  40
#define DIM   768
#define LSUF  31

#define MAT_ELEMS 90439680u      // 32*92*40*768  (f32 elements)
#define MASK_BASE 180879360u     // 2*MAT_ELEMS (f32 element offset)

#define NBLK_CTX  256u           // (which, pair, cls-group of 23)
#define NBLK_D1   1472u          // (which, cls, token-quad)
#define NBLK_MASK 115u           // 115*256*4 = 117760 mask elems
#define NBLK_ALL  (NBLK_CTX + NBLK_D1 + NBLK_MASK)   // 1843

// ONE kernel, byte-balanced blocks:
//   ctx role  : 552 KB/block (23 cls x 8 tokens x 3 KB), MLP recomputed in-block
//   copy role : 384 KB/block (12 KB staged once -> 32 pairs)
//   mask role : tail
// NT stores throughout (R10 A/B: plain stores cost +17us).
__global__ __launch_bounds__(256) void k_fused(
    const int* __restrict__ so_ids,     // (32,2) int32
    const float* __restrict__ enti,     // (36,256)
    const float* __restrict__ prefix,   // (133,1,768)
    const float* __restrict__ suffix,   // (133,31,768)
    const int* __restrict__ tok_mask,   // (133,40) int32
    const float* __restrict__ meta,     // (8,768)
    const float* __restrict__ sctx,     // (8,768)
    const float* __restrict__ octx,     // (8,768)
    const float* __restrict__ W1,       // (512,256)
    const float* __restrict__ b1,       // (256)
    const float* __restrict__ W2,       // (256,1536)
    float* __restrict__ out)
{
    const u32 bid = blockIdx.x;
    const u32 t = threadIdx.x;
    __shared__ __align__(16) float arena[8 * DIM];   // 24 KB
    __shared__ int ids[2];

    if (bid < NBLK_CTX) {
        // ---------------- ctx role ----------------
        const u32 which = bid / 128u;
        const u32 rem = bid - which * 128u;
        const u32 pair = rem / 4u;
        const u32 cg = rem & 3u;

        if (t == 0) {
            bool is64 = true;
            for (int i = 1; i < 64; i += 2) is64 = is64 && (so_ids[i] == 0);
            if (is64) { ids[0] = so_ids[4 * pair]; ids[1] = so_ids[4 * pair + 2]; }
            else      { ids[0] = so_ids[2 * pair]; ids[1] = so_ids[2 * pair + 1]; }
        }
        __syncthreads();

        float* so_vec = arena;            // [0, 512)
        float* h      = arena + 512;      // [512, 768)
        float* red    = arena + 768;      // [768, 2816)  8x256
        float* probs  = arena + 2816;     // [2816, 2824)

        so_vec[t]        = enti[ids[0] * 256 + t];
        so_vec[256 + t]  = enti[ids[1] * 256 + t];
        __syncthreads();

        // h = relu(so @ W1 + b1): thread t owns column t
        {
            float acc = b1[t];
            const float* w = W1 + t;
            #pragma unroll 8
            for (int k = 0; k < 512; ++k)
                acc = fmaf(so_vec[k], w[(size_t)k * 256], acc);
            h[t] = fmaxf(acc, 0.f);
        }
        __syncthreads();

        // q = (h @ W2)[which*768 ..]: thread t owns cols t, t+256, t+512 (in regs)
        float qr[3] = {0.f, 0.f, 0.f};
        {
            const float* w = W2 + which * DIM + t;
            #pragma unroll 4
            for (int k = 0; k < 256; ++k) {
                const float hk = h[k];
                #pragma unroll
                for (int i = 0; i < 3; ++i)
                    qr[i] = fmaf(hk, w[(size_t)k * 1536 + i * 256], qr[i]);
            }
        }

        // scores vs 8 meta rows
        #pragma unroll
        for (int c = 0; c < 8; ++c) {
            float pp = 0.f;
            #pragma unroll
            for (int i = 0; i < 3; ++i)
                pp = fmaf(qr[i], meta[c * DIM + t + 256 * i], pp);
            red[c * 256 + t] = pp;
        }
        __syncthreads();
        for (int s = 128; s > 0; s >>= 1) {
            if (t < (u32)s) {
                #pragma unroll
                for (int c = 0; c < 8; ++c)
                    red[c * 256 + t] += red[c * 256 + t + s];
            }
            __syncthreads();
        }
        if (t == 0) {
            const float scale = 0.036084391824351615f;  // 1/sqrt(768)
            float sc[8], m = -1e30f;
            #pragma unroll
            for (int c = 0; c < 8; ++c) { sc[c] = red[c * 256] * scale; m = fmaxf(m, sc[c]); }
            float sum = 0.f;
            #pragma unroll
            for (int c = 0; c < 8; ++c) { sc[c] = expf(sc[c] - m); sum += sc[c]; }
            const float inv = 1.f / sum;
            #pragma unroll
            for (int c = 0; c < 8; ++c) probs[c] = sc[c] * inv;
        }
        __syncthreads();

        float pr[8];
        #pragma unroll
        for (int c = 0; c < 8; ++c) pr[c] = probs[c];
        float att_d[3];
        #pragma unroll
        for (int i = 0; i < 3; ++i) {
            const int d = t + 256 * i;
            float a = 0.f;
            #pragma unroll
            for (int c = 0; c < 8; ++c)
                a = fmaf(pr[c], meta[c * DIM + d], a);
            att_d[i] = a;
        }
        __syncthreads();   // arena fully dead

        // build the 8 summed rows (ctx + att) in LDS
        const float* ctxg = which ? octx : sctx;
        #pragma unroll
        for (int j = 0; j < 8; ++j) {
            #pragma unroll
            for (int i = 0; i < 3; ++i) {
                const int d = t + 256 * i;
                arena[j * DIM + d] = ctxg[j * DIM + d] + att_d[i];
            }
        }
        __syncthreads();

        // stream the 24 KB block to this block's 23 cls slabs (tokens 1..8)
        float* base = out + (size_t)which * MAT_ELEMS
                          + ((size_t)(pair * NCLS) * MAXL + 1u) * DIM;
        for (u32 c = 0; c < 23u; ++c) {
            const u32 cls = cg * 23u + c;
            float* bc = base + (size_t)cls * (MAXL * DIM);
            #pragma unroll
            for (u32 uu = 0; uu < 6u; ++uu) {
                const u32 u = uu * 256u + t;
                __builtin_nontemporal_store(*(const f32x4*)(arena + u * 4u),
                                            (f32x4*)(bc + u * 4u));
            }
        }
    } else if (bid < NBLK_CTX + NBLK_D1) {
        // ---------------- copy role: prefix/suffix replicator (LDS-staged) ----------------
        const u32 r = bid - NBLK_CTX;
        const u32 which = r / (NCLS * 8u);
        const u32 rem = r - which * (NCLS * 8u);
        const u32 cls = rem / 8u;
        const u32 tq = rem - cls * 8u;

        for (u32 u = t; u < 4u * 192u; u += 256u) {   // 768 f32x4 units (12 KB)
            const u32 j = u / 192u;
            const u32 dpos = u - j * 192u;
            const u32 rtok = (tq == 0u) ? (j == 0u ? 0u : 8u + j) : (8u + 4u * tq + j);
            const float* src = (rtok == 0u)
                ? (prefix + (size_t)(cls + 1u) * DIM + dpos * 4u)
                : (suffix + ((size_t)(cls + 1u) * LSUF + (rtok - 9u)) * DIM + dpos * 4u);
            *(f32x4*)(arena + u * 4u) = *(const f32x4*)src;
        }
        __syncthreads();

        for (u32 pair = 0; pair < NPAIR; ++pair) {
            float* slab = out + (size_t)which * MAT_ELEMS
                              + ((size_t)(pair * NCLS + cls) * MAXL) * DIM;
            #pragma unroll
            for (u32 uu = 0; uu < 3u; ++uu) {
                const u32 u = uu * 256u + t;
                const u32 j = u / 192u;                     // wave-uniform
                const u32 dpos = u - j * 192u;
                const u32 rtok = (tq == 0u) ? (j == 0u ? 0u : 8u + j) : (8u + 4u * tq + j);
                __builtin_nontemporal_store(*(const f32x4*)(arena + u * 4u),
                    (f32x4*)(slab + (size_t)rtok * DIM + dpos * 4u));
            }
        }
    } else {
        // ---------------- mask role ----------------
        const u32 idx4 = (bid - NBLK_CTX - NBLK_D1) * 256u + t;
        const u32 m = idx4 * 4u;
        f32x4 v;
        #pragma unroll
        for (int j = 0; j < 4; ++j) {
            const u32 i = m + (u32)j;
            const u32 rw = i / 40u;
            const u32 tk = i - rw * 40u;
            const u32 cls = rw % 92u;
            v[j] = (float)tok_mask[(cls + 1u) * 40u + tk];
        }
        __builtin_nontemporal_store(v, (f32x4*)(out + MASK_BASE + m));
    }
}

extern "C" void kernel_launch(void* const* d_in, const int* in_sizes, int n_in,
                              void* d_out, int out_size, void* d_ws, size_t ws_size,
                              hipStream_t stream) {
    const int* so_ids     = (const int*)d_in[0];
    const float* enti     = (const float*)d_in[1];
    const float* prefix   = (const float*)d_in[2];
    const float* suffix   = (const float*)d_in[3];
    const int* tok_mask   = (const int*)d_in[4];
    const float* meta     = (const float*)d_in[5];
    const float* sctx     = (const float*)d_in[6];
    const float* octx     = (const float*)d_in[7];
    const float* W1       = (const float*)d_in[8];
    const float* b1       = (const float*)d_in[9];
    const float* W2       = (const float*)d_in[10];

    k_fused<<<dim3(NBLK_ALL), dim3(256), 0, stream>>>(
        so_ids, enti, prefix, suffix, tok_mask, meta, sctx, octx, W1, b1, W2,
        (float*)d_out);
}